// Round 1
// baseline (388.278 us; speedup 1.0000x reference)
//
#include <hip/hip_runtime.h>
#include <hip/hip_bf16.h>

typedef __bf16 v8bf __attribute__((ext_vector_type(8)));
typedef float  v4f  __attribute__((ext_vector_type(4)));

#define T_LEN 2048
#define NH 16
#define HD 64
#define BH 32
#define C_DIM 1024

// workspace byte offsets
#define WS_X1B  ((size_t)0)
#define WS_X2B  ((size_t)8  << 20)
#define WS_W    ((size_t)16 << 20)   // wq,wk,wv,wp bf16, 2MB each
#define WS_CTAB ((size_t)24 << 20)
#define WS_STAB (WS_CTAB + 262144)
#define WS_Q    ((size_t)25 << 20)
#define WS_K    ((size_t)33 << 20)
#define WS_VT   ((size_t)41 << 20)
#define WS_O    ((size_t)0)          // overlaps X1B (dead by then)

__device__ __forceinline__ unsigned short f2bf(float f) {
  unsigned int u = __float_as_uint(f);
  u += 0x7fffu + ((u >> 16) & 1u);
  return (unsigned short)(u >> 16);
}
__device__ __forceinline__ float bf2f(unsigned short h) {
  return __uint_as_float(((unsigned int)h) << 16);
}

// ---------------- fp32 -> bf16 conversion (x1, x2, wq, wk, wv, wp) -------------
__global__ __launch_bounds__(256) void cvt_kernel(
    const float* __restrict__ x1, const float* __restrict__ x2,
    const float* __restrict__ wq, const float* __restrict__ wk,
    const float* __restrict__ wv, const float* __restrict__ wp,
    unsigned short* __restrict__ x1b, unsigned short* __restrict__ x2b,
    unsigned short* __restrict__ wqb) {
  int i = blockIdx.x * 256 + threadIdx.x;   // float4 index, total 3M
  if (i >= 3145728) return;
  const float* s; unsigned short* d; int off;
  if (i < 1048576) { s = x1; d = x1b; off = i; }
  else if (i < 2097152) { s = x2; d = x2b; off = i - 1048576; }
  else {
    int j = i - 2097152;
    int w = j >> 18;            // 0..3 (wq,wk,wv,wp: 256K float4 each)
    off = j & 262143;
    s = (w == 0) ? wq : (w == 1) ? wk : (w == 2) ? wv : wp;
    d = wqb + ((size_t)w * 1048576);
  }
  float4 v = ((const float4*)s)[off];
  ushort4 o;
  o.x = f2bf(v.x); o.y = f2bf(v.y); o.z = f2bf(v.z); o.w = f2bf(v.w);
  ((ushort4*)d)[off] = o;
}

// ---------------- RoPE tables ----------------
__global__ __launch_bounds__(256) void tab_kernel(float* __restrict__ ctab,
                                                  float* __restrict__ stab) {
  int i = blockIdx.x * 256 + threadIdx.x;   // 65536 = 2048*32
  int t = i >> 5, f = i & 31;
  float freq = powf(10000.0f, -(float)f * (1.0f / 32.0f));
  float a = (float)t * freq;
  ctab[i] = cosf(a);
  stab[i] = sinf(a);
}

// ---------------- QKV GEMM: [4096,1024] x [1024,1024]^T + bias -----------------
// z=0: Q <- x1*wq^T+bq   -> [bh][t][d] bf16
// z=1: K <- x2*wk^T+bk   -> [bh][t][d] bf16
// z=2: V -> stored transposed [bh][d][t] bf16
__global__ __launch_bounds__(256) void qkv_gemm(
    const unsigned short* __restrict__ x1b, const unsigned short* __restrict__ x2b,
    const unsigned short* __restrict__ wall,
    const float* __restrict__ bq, const float* __restrict__ bk,
    const float* __restrict__ bv,
    unsigned short* __restrict__ Qd, unsigned short* __restrict__ Kd,
    unsigned short* __restrict__ VTd) {
  int z = blockIdx.z;
  const unsigned short* A = (z == 0) ? x1b : x2b;
  const unsigned short* W = wall + (size_t)z * 1048576;
  const float* bias = (z == 0) ? bq : (z == 1) ? bk : bv;

  __shared__ unsigned short lds[8192];   // A tile [128][32] @0, B tile @4096
  int tid = threadIdx.x;
  int wave = tid >> 6, lane = tid & 63;
  int wm = wave >> 1, wn = wave & 1;
  int r = lane & 15, g = lane >> 4;
  int m0 = blockIdx.y * 128, n0 = blockIdx.x * 128;

  v4f zero = {0.f, 0.f, 0.f, 0.f};
  v4f acc[4][4];
#pragma unroll
  for (int i = 0; i < 4; ++i)
#pragma unroll
    for (int j = 0; j < 4; ++j) acc[i][j] = zero;

  for (int k0 = 0; k0 < 1024; k0 += 32) {
    const unsigned short* Ab = A + (size_t)m0 * 1024 + k0;
    const unsigned short* Bb = W + (size_t)n0 * 1024 + k0;
#pragma unroll
    for (int it = 0; it < 2; ++it) {
      int c = it * 256 + tid;
      __builtin_amdgcn_global_load_lds(
          (const __attribute__((address_space(1))) void*)(Ab + (size_t)(c >> 2) * 1024 + (c & 3) * 8),
          (__attribute__((address_space(3))) void*)(lds + it * 2048 + wave * 512),
          16, 0, 0);
      __builtin_amdgcn_global_load_lds(
          (const __attribute__((address_space(1))) void*)(Bb + (size_t)(c >> 2) * 1024 + (c & 3) * 8),
          (__attribute__((address_space(3))) void*)(lds + 4096 + it * 2048 + wave * 512),
          16, 0, 0);
    }
    __syncthreads();
    v8bf af[4], bfr[4];
#pragma unroll
    for (int mf = 0; mf < 4; ++mf)
      af[mf] = *(const v8bf*)(lds + (wm * 64 + mf * 16 + r) * 32 + g * 8);
#pragma unroll
    for (int nf = 0; nf < 4; ++nf)
      bfr[nf] = *(const v8bf*)(lds + 4096 + (wn * 64 + nf * 16 + r) * 32 + g * 8);
#pragma unroll
    for (int mf = 0; mf < 4; ++mf)
#pragma unroll
      for (int nf = 0; nf < 4; ++nf)
        acc[mf][nf] = __builtin_amdgcn_mfma_f32_16x16x32_bf16(af[mf], bfr[nf], acc[mf][nf], 0, 0, 0);
    __syncthreads();
  }

#pragma unroll
  for (int nf = 0; nf < 4; ++nf) {
    int col = n0 + wn * 64 + nf * 16 + r;
    float bv_ = bias[col];
    int h = col >> 6, d = col & 63;
#pragma unroll
    for (int mf = 0; mf < 4; ++mf) {
      int row0 = m0 + wm * 64 + mf * 16 + g * 4;
      int b = row0 >> 11, t0 = row0 & 2047;
      if (z < 2) {
        unsigned short* dst = (z == 0) ? Qd : Kd;
#pragma unroll
        for (int rg = 0; rg < 4; ++rg)
          dst[(((size_t)(b * NH + h)) * T_LEN + t0 + rg) * HD + d] = f2bf(acc[mf][nf][rg] + bv_);
      } else {
        ushort4 pk;
        pk.x = f2bf(acc[mf][nf][0] + bv_);
        pk.y = f2bf(acc[mf][nf][1] + bv_);
        pk.z = f2bf(acc[mf][nf][2] + bv_);
        pk.w = f2bf(acc[mf][nf][3] + bv_);
        *(ushort4*)(VTd + (((size_t)(b * NH + h)) * HD + d) * T_LEN + t0) = pk;
      }
    }
  }
}

// ---------------- RoPE in-place on Q (scaled 1/8) and K ----------------
__global__ __launch_bounds__(256) void rope_kernel(
    unsigned short* __restrict__ Qd, unsigned short* __restrict__ Kd,
    const float* __restrict__ ctab, const float* __restrict__ stab) {
  int i = blockIdx.x * 256 + threadIdx.x;  // 2 * 524288 chunks of 8 elems
  int arr = i >> 19;
  int j = i & 524287;
  unsigned short* base = arr ? Kd : Qd;
  float scale = arr ? 1.0f : 0.125f;       // fold D^-1/2 into Q (exact, pow2)
  int d8 = j & 7;
  int t = (j >> 3) & 2047;
  uint4 raw = *(const uint4*)(base + (size_t)j * 8);
  int f0 = (t << 5) + (d8 << 2);
  unsigned int* pw = &raw.x;
#pragma unroll
  for (int p = 0; p < 4; ++p) {
    unsigned int w = pw[p];
    float x0 = bf2f((unsigned short)(w & 0xffffu));
    float x1v = bf2f((unsigned short)(w >> 16));
    float c = ctab[f0 + p], sn = stab[f0 + p];
    float o0 = (x0 * c - x1v * sn) * scale;
    float o1 = (x0 * sn + x1v * c) * scale;
    pw[p] = (unsigned int)f2bf(o0) | ((unsigned int)f2bf(o1) << 16);
  }
  *(uint4*)(base + (size_t)j * 8) = raw;
}

// ---------------- flash attention, mask j <= i + 64 ----------------
// grid (32 qtiles reversed, 32 bh), 4 waves x 16 q-rows
__global__ __launch_bounds__(256) void attn_kernel(
    const unsigned short* __restrict__ Qd, const unsigned short* __restrict__ Kd,
    const unsigned short* __restrict__ VTd, unsigned short* __restrict__ Od) {
  int bh = blockIdx.y;
  int qt = (int)gridDim.x - 1 - (int)blockIdx.x;  // heavy tiles first
  int q0 = qt * 64;
  int tid = threadIdx.x, wave = tid >> 6, lane = tid & 63;
  int r = lane & 15, g = lane >> 4;
  int qrow0 = q0 + wave * 16;
  const unsigned short* Qp = Qd + (size_t)bh * T_LEN * HD;
  const unsigned short* Kp = Kd + (size_t)bh * T_LEN * HD;
  const unsigned short* Vp = VTd + (size_t)bh * HD * T_LEN;

  v8bf qf0 = *(const v8bf*)(Qp + (qrow0 + r) * HD + g * 8);
  v8bf qf1 = *(const v8bf*)(Qp + (qrow0 + r) * HD + 32 + g * 8);

  v4f zero = {0.f, 0.f, 0.f, 0.f};
  v4f oacc[4];
#pragma unroll
  for (int i = 0; i < 4; ++i) oacc[i] = zero;
  float mi[4] = {-1e30f, -1e30f, -1e30f, -1e30f};
  float li[4] = {0.f, 0.f, 0.f, 0.f};

  __shared__ unsigned short plds[4][16][64];   // per-wave P transpose buffer

  int ktiles = qt + 2; if (ktiles > 32) ktiles = 32;
  for (int kt = 0; kt < ktiles; ++kt) {
    int j0 = kt * 64;
    v4f s[4];
#pragma unroll
    for (int nt = 0; nt < 4; ++nt) {
      const unsigned short* kb = Kp + (size_t)(j0 + nt * 16 + r) * HD + g * 8;
      v8bf b0 = *(const v8bf*)kb;
      v8bf b1 = *(const v8bf*)(kb + 32);
      v4f a = zero;
      a = __builtin_amdgcn_mfma_f32_16x16x32_bf16(qf0, b0, a, 0, 0, 0);
      a = __builtin_amdgcn_mfma_f32_16x16x32_bf16(qf1, b1, a, 0, 0, 0);
      s[nt] = a;
    }
    if (j0 + 63 > qrow0 + 64) {   // only boundary tiles need the mask
#pragma unroll
      for (int nt = 0; nt < 4; ++nt)
#pragma unroll
        for (int rg = 0; rg < 4; ++rg) {
          int qi = qrow0 + g * 4 + rg;
          int kj = j0 + nt * 16 + r;
          if (kj > qi + 64) s[nt][rg] = -1e30f;
        }
    }
    float pm[4], al[4], rs[4];
#pragma unroll
    for (int rg = 0; rg < 4; ++rg)
      pm[rg] = fmaxf(fmaxf(s[0][rg], s[1][rg]), fmaxf(s[2][rg], s[3][rg]));
#pragma unroll
    for (int off = 1; off < 16; off <<= 1)
#pragma unroll
      for (int rg = 0; rg < 4; ++rg)
        pm[rg] = fmaxf(pm[rg], __shfl_xor(pm[rg], off, 64));
#pragma unroll
    for (int rg = 0; rg < 4; ++rg) {
      float mn = fmaxf(mi[rg], pm[rg]);
      al[rg] = __expf(mi[rg] - mn);
      mi[rg] = mn;
      rs[rg] = 0.f;
    }
#pragma unroll
    for (int nt = 0; nt < 4; ++nt)
#pragma unroll
      for (int rg = 0; rg < 4; ++rg) {
        float p = __expf(s[nt][rg] - mi[rg]);
        s[nt][rg] = p;
        rs[rg] += p;
      }
#pragma unroll
    for (int off = 1; off < 16; off <<= 1)
#pragma unroll
      for (int rg = 0; rg < 4; ++rg)
        rs[rg] += __shfl_xor(rs[rg], off, 64);
#pragma unroll
    for (int rg = 0; rg < 4; ++rg)
      li[rg] = li[rg] * al[rg] + rs[rg];
#pragma unroll
    for (int nt = 0; nt < 4; ++nt)
#pragma unroll
      for (int rg = 0; rg < 4; ++rg)
        oacc[nt][rg] *= al[rg];
    // transpose P (C-layout) -> A-layout via per-wave LDS
#pragma unroll
    for (int nt = 0; nt < 4; ++nt)
#pragma unroll
      for (int rg = 0; rg < 4; ++rg)
        plds[wave][g * 4 + rg][nt * 16 + r] = f2bf(s[nt][rg]);
    __syncthreads();
    v8bf pa0 = *(const v8bf*)(&plds[wave][r][g * 8]);
    v8bf pa1 = *(const v8bf*)(&plds[wave][r][32 + g * 8]);
#pragma unroll
    for (int nt = 0; nt < 4; ++nt) {
      const unsigned short* vb = Vp + (size_t)(nt * 16 + r) * T_LEN + j0 + g * 8;
      v8bf v0 = *(const v8bf*)vb;
      v8bf v1 = *(const v8bf*)(vb + 32);
      oacc[nt] = __builtin_amdgcn_mfma_f32_16x16x32_bf16(pa0, v0, oacc[nt], 0, 0, 0);
      oacc[nt] = __builtin_amdgcn_mfma_f32_16x16x32_bf16(pa1, v1, oacc[nt], 0, 0, 0);
    }
  }
#pragma unroll
  for (int rg = 0; rg < 4; ++rg) li[rg] = 1.0f / li[rg];
#pragma unroll
  for (int nt = 0; nt < 4; ++nt)
#pragma unroll
    for (int rg = 0; rg < 4; ++rg)
      Od[((size_t)bh * T_LEN + qrow0 + g * 4 + rg) * HD + nt * 16 + r] =
          f2bf(oacc[nt][rg] * li[rg]);
}

// ---------------- output projection: out = O @ wp^T (fp32 out) ----------------
__global__ __launch_bounds__(256) void proj_gemm(
    const unsigned short* __restrict__ Ob, const unsigned short* __restrict__ Wpb,
    float* __restrict__ out) {
  __shared__ unsigned short lds[8192];
  int tid = threadIdx.x;
  int wave = tid >> 6, lane = tid & 63;
  int wm = wave >> 1, wn = wave & 1;
  int r = lane & 15, g = lane >> 4;
  int m0 = blockIdx.y * 128, n0 = blockIdx.x * 128;

  v4f zero = {0.f, 0.f, 0.f, 0.f};
  v4f acc[4][4];
#pragma unroll
  for (int i = 0; i < 4; ++i)
#pragma unroll
    for (int j = 0; j < 4; ++j) acc[i][j] = zero;

  for (int k0 = 0; k0 < 1024; k0 += 32) {
#pragma unroll
    for (int it = 0; it < 2; ++it) {
      int c = it * 256 + tid;
      int row = m0 + (c >> 2);
      int b = row >> 11, t = row & 2047;
      int k = k0 + (c & 3) * 8;
      int h = k >> 6, d = k & 63;
      __builtin_amdgcn_global_load_lds(
          (const __attribute__((address_space(1))) void*)(Ob + (((size_t)(b * NH + h)) * T_LEN + t) * HD + d),
          (__attribute__((address_space(3))) void*)(lds + it * 2048 + wave * 512),
          16, 0, 0);
      __builtin_amdgcn_global_load_lds(
          (const __attribute__((address_space(1))) void*)(Wpb + (size_t)(n0 + (c >> 2)) * 1024 + k0 + (c & 3) * 8),
          (__attribute__((address_space(3))) void*)(lds + 4096 + it * 2048 + wave * 512),
          16, 0, 0);
    }
    __syncthreads();
    v8bf af[4], bfr[4];
#pragma unroll
    for (int mf = 0; mf < 4; ++mf)
      af[mf] = *(const v8bf*)(lds + (wm * 64 + mf * 16 + r) * 32 + g * 8);
#pragma unroll
    for (int nf = 0; nf < 4; ++nf)
      bfr[nf] = *(const v8bf*)(lds + 4096 + (wn * 64 + nf * 16 + r) * 32 + g * 8);
#pragma unroll
    for (int mf = 0; mf < 4; ++mf)
#pragma unroll
      for (int nf = 0; nf < 4; ++nf)
        acc[mf][nf] = __builtin_amdgcn_mfma_f32_16x16x32_bf16(af[mf], bfr[nf], acc[mf][nf], 0, 0, 0);
    __syncthreads();
  }
#pragma unroll
  for (int mf = 0; mf < 4; ++mf)
#pragma unroll
    for (int nf = 0; nf < 4; ++nf) {
      int col = n0 + wn * 64 + nf * 16 + r;
      int row0 = m0 + wm * 64 + mf * 16 + g * 4;
#pragma unroll
      for (int rg = 0; rg < 4; ++rg)
        out[(size_t)(row0 + rg) * 1024 + col] = acc[mf][nf][rg];
    }
}

extern "C" void kernel_launch(void* const* d_in, const int* in_sizes, int n_in,
                              void* d_out, int out_size, void* d_ws, size_t ws_size,
                              hipStream_t stream) {
  const float* x1 = (const float*)d_in[0];
  const float* x2 = (const float*)d_in[1];
  const float* wq = (const float*)d_in[2];
  const float* bq = (const float*)d_in[3];
  const float* wk = (const float*)d_in[4];
  const float* bk = (const float*)d_in[5];
  const float* wv = (const float*)d_in[6];
  const float* bv = (const float*)d_in[7];
  const float* wp = (const float*)d_in[8];
  float* out = (float*)d_out;
  char* ws = (char*)d_ws;

  unsigned short* x1b = (unsigned short*)(ws + WS_X1B);
  unsigned short* x2b = (unsigned short*)(ws + WS_X2B);
  unsigned short* wqb = (unsigned short*)(ws + WS_W);
  unsigned short* wpb = wqb + 3 * 1048576;
  float* ctab = (float*)(ws + WS_CTAB);
  float* stab = (float*)(ws + WS_STAB);
  unsigned short* Qd = (unsigned short*)(ws + WS_Q);
  unsigned short* Kd = (unsigned short*)(ws + WS_K);
  unsigned short* VTd = (unsigned short*)(ws + WS_VT);
  unsigned short* Od = (unsigned short*)(ws + WS_O);

  cvt_kernel<<<12288, 256, 0, stream>>>(x1, x2, wq, wk, wv, wp, x1b, x2b, wqb);
  tab_kernel<<<256, 256, 0, stream>>>(ctab, stab);
  qkv_gemm<<<dim3(8, 32, 3), 256, 0, stream>>>(x1b, x2b, wqb, bq, bk, bv, Qd, Kd, VTd);
  rope_kernel<<<4096, 256, 0, stream>>>(Qd, Kd, ctab, stab);
  attn_kernel<<<dim3(32, 32), 256, 0, stream>>>(Qd, Kd, VTd, Od);
  proj_gemm<<<dim3(8, 32), 256, 0, stream>>>(Od, wpb, out);
}

// Round 2
// 210.595 us; speedup vs baseline: 1.8437x; 1.8437x over previous
//
#include <hip/hip_runtime.h>
#include <hip/hip_bf16.h>

typedef __bf16 v8bf __attribute__((ext_vector_type(8)));
typedef float  v4f  __attribute__((ext_vector_type(4)));

#define T_LEN 2048
#define NH 16
#define HD 64
#define BH 32
#define C_DIM 1024

// workspace byte offsets
#define WS_X1B  ((size_t)0)
#define WS_X2B  ((size_t)8  << 20)
#define WS_W    ((size_t)16 << 20)   // wq,wk,wv,wp bf16, 2MB each
#define WS_CTAB ((size_t)24 << 20)
#define WS_STAB (WS_CTAB + 262144)
#define WS_Q    ((size_t)25 << 20)
#define WS_K    ((size_t)33 << 20)
#define WS_VT   ((size_t)41 << 20)
#define WS_O    ((size_t)0)          // overlaps X1B (dead by then)

__device__ __forceinline__ unsigned short f2bf(float f) {
  unsigned int u = __float_as_uint(f);
  u += 0x7fffu + ((u >> 16) & 1u);
  return (unsigned short)(u >> 16);
}
__device__ __forceinline__ float bf2f(unsigned short h) {
  return __uint_as_float(((unsigned int)h) << 16);
}

// ---------------- fp32 -> bf16 conversion (x1, x2, wq, wk, wv, wp) -------------
__global__ __launch_bounds__(256) void cvt_kernel(
    const float* __restrict__ x1, const float* __restrict__ x2,
    const float* __restrict__ wq, const float* __restrict__ wk,
    const float* __restrict__ wv, const float* __restrict__ wp,
    unsigned short* __restrict__ x1b, unsigned short* __restrict__ x2b,
    unsigned short* __restrict__ wqb) {
  int i = blockIdx.x * 256 + threadIdx.x;   // float4 index, total 3M
  if (i >= 3145728) return;
  const float* s; unsigned short* d; int off;
  if (i < 1048576) { s = x1; d = x1b; off = i; }
  else if (i < 2097152) { s = x2; d = x2b; off = i - 1048576; }
  else {
    int j = i - 2097152;
    int w = j >> 18;            // 0..3 (wq,wk,wv,wp: 256K float4 each)
    off = j & 262143;
    s = (w == 0) ? wq : (w == 1) ? wk : (w == 2) ? wv : wp;
    d = wqb + ((size_t)w * 1048576);
  }
  float4 v = ((const float4*)s)[off];
  ushort4 o;
  o.x = f2bf(v.x); o.y = f2bf(v.y); o.z = f2bf(v.z); o.w = f2bf(v.w);
  ((ushort4*)d)[off] = o;
}

// ---------------- RoPE tables ----------------
__global__ __launch_bounds__(256) void tab_kernel(float* __restrict__ ctab,
                                                  float* __restrict__ stab) {
  int i = blockIdx.x * 256 + threadIdx.x;   // 65536 = 2048*32
  int t = i >> 5, f = i & 31;
  float freq = powf(10000.0f, -(float)f * (1.0f / 32.0f));
  float a = (float)t * freq;
  ctab[i] = cosf(a);
  stab[i] = sinf(a);
}

// ---------------- QKV GEMM: [4096,1024] x [1024,1024]^T + bias -----------------
__global__ __launch_bounds__(256) void qkv_gemm(
    const unsigned short* __restrict__ x1b, const unsigned short* __restrict__ x2b,
    const unsigned short* __restrict__ wall,
    const float* __restrict__ bq, const float* __restrict__ bk,
    const float* __restrict__ bv,
    unsigned short* __restrict__ Qd, unsigned short* __restrict__ Kd,
    unsigned short* __restrict__ VTd) {
  int z = blockIdx.z;
  const unsigned short* A = (z == 0) ? x1b : x2b;
  const unsigned short* W = wall + (size_t)z * 1048576;
  const float* bias = (z == 0) ? bq : (z == 1) ? bk : bv;

  __shared__ unsigned short lds[8192];   // A tile [128][32] @0, B tile @4096
  int tid = threadIdx.x;
  int wave = tid >> 6, lane = tid & 63;
  int wm = wave >> 1, wn = wave & 1;
  int r = lane & 15, g = lane >> 4;
  int m0 = blockIdx.y * 128, n0 = blockIdx.x * 128;

  v4f zero = {0.f, 0.f, 0.f, 0.f};
  v4f acc[4][4];
#pragma unroll
  for (int i = 0; i < 4; ++i)
#pragma unroll
    for (int j = 0; j < 4; ++j) acc[i][j] = zero;

  for (int k0 = 0; k0 < 1024; k0 += 32) {
    const unsigned short* Ab = A + (size_t)m0 * 1024 + k0;
    const unsigned short* Bb = W + (size_t)n0 * 1024 + k0;
#pragma unroll
    for (int it = 0; it < 2; ++it) {
      int c = it * 256 + tid;
      __builtin_amdgcn_global_load_lds(
          (const __attribute__((address_space(1))) void*)(Ab + (size_t)(c >> 2) * 1024 + (c & 3) * 8),
          (__attribute__((address_space(3))) void*)(lds + it * 2048 + wave * 512),
          16, 0, 0);
      __builtin_amdgcn_global_load_lds(
          (const __attribute__((address_space(1))) void*)(Bb + (size_t)(c >> 2) * 1024 + (c & 3) * 8),
          (__attribute__((address_space(3))) void*)(lds + 4096 + it * 2048 + wave * 512),
          16, 0, 0);
    }
    __syncthreads();
    v8bf af[4], bfr[4];
#pragma unroll
    for (int mf = 0; mf < 4; ++mf)
      af[mf] = *(const v8bf*)(lds + (wm * 64 + mf * 16 + r) * 32 + g * 8);
#pragma unroll
    for (int nf = 0; nf < 4; ++nf)
      bfr[nf] = *(const v8bf*)(lds + 4096 + (wn * 64 + nf * 16 + r) * 32 + g * 8);
#pragma unroll
    for (int mf = 0; mf < 4; ++mf)
#pragma unroll
      for (int nf = 0; nf < 4; ++nf)
        acc[mf][nf] = __builtin_amdgcn_mfma_f32_16x16x32_bf16(af[mf], bfr[nf], acc[mf][nf], 0, 0, 0);
    __syncthreads();
  }

#pragma unroll
  for (int nf = 0; nf < 4; ++nf) {
    int col = n0 + wn * 64 + nf * 16 + r;
    float bv_ = bias[col];
    int h = col >> 6, d = col & 63;
#pragma unroll
    for (int mf = 0; mf < 4; ++mf) {
      int row0 = m0 + wm * 64 + mf * 16 + g * 4;
      int b = row0 >> 11, t0 = row0 & 2047;
      if (z < 2) {
        unsigned short* dst = (z == 0) ? Qd : Kd;
#pragma unroll
        for (int rg = 0; rg < 4; ++rg)
          dst[(((size_t)(b * NH + h)) * T_LEN + t0 + rg) * HD + d] = f2bf(acc[mf][nf][rg] + bv_);
      } else {
        ushort4 pk;
        pk.x = f2bf(acc[mf][nf][0] + bv_);
        pk.y = f2bf(acc[mf][nf][1] + bv_);
        pk.z = f2bf(acc[mf][nf][2] + bv_);
        pk.w = f2bf(acc[mf][nf][3] + bv_);
        *(ushort4*)(VTd + (((size_t)(b * NH + h)) * HD + d) * T_LEN + t0) = pk;
      }
    }
  }
}

// ---------------- RoPE in-place on Q (scaled 1/8) and K ----------------
__global__ __launch_bounds__(256) void rope_kernel(
    unsigned short* __restrict__ Qd, unsigned short* __restrict__ Kd,
    const float* __restrict__ ctab, const float* __restrict__ stab) {
  int i = blockIdx.x * 256 + threadIdx.x;  // 2 * 524288 chunks of 8 elems
  int arr = i >> 19;
  int j = i & 524287;
  unsigned short* base = arr ? Kd : Qd;
  float scale = arr ? 1.0f : 0.125f;       // fold D^-1/2 into Q (exact, pow2)
  int d8 = j & 7;
  int t = (j >> 3) & 2047;
  uint4 raw = *(const uint4*)(base + (size_t)j * 8);
  int f0 = (t << 5) + (d8 << 2);
  unsigned int* pw = &raw.x;
#pragma unroll
  for (int p = 0; p < 4; ++p) {
    unsigned int w = pw[p];
    float x0 = bf2f((unsigned short)(w & 0xffffu));
    float x1v = bf2f((unsigned short)(w >> 16));
    float c = ctab[f0 + p], sn = stab[f0 + p];
    float o0 = (x0 * c - x1v * sn) * scale;
    float o1 = (x0 * sn + x1v * c) * scale;
    pw[p] = (unsigned int)f2bf(o0) | ((unsigned int)f2bf(o1) << 16);
  }
  *(uint4*)(base + (size_t)j * 8) = raw;
}

// ---------------- flash attention, mask j <= i + 64 ----------------
// grid (32 qtiles reversed, 32 bh), 4 waves x 16 q-rows
// K/V tiles staged in LDS (double-buffered, XOR-swizzled), shared by all waves.
__global__ __launch_bounds__(256) void attn_kernel(
    const unsigned short* __restrict__ Qd, const unsigned short* __restrict__ Kd,
    const unsigned short* __restrict__ VTd, unsigned short* __restrict__ Od) {
  int bh = blockIdx.y;
  int qt = (int)gridDim.x - 1 - (int)blockIdx.x;  // heavy tiles first
  int q0 = qt * 64;
  int tid = threadIdx.x, wave = tid >> 6, lane = tid & 63;
  int r = lane & 15, g = lane >> 4;
  int qrow0 = q0 + wave * 16;
  const unsigned short* Qp = Qd + (size_t)bh * T_LEN * HD;
  const unsigned short* Kp = Kd + (size_t)bh * T_LEN * HD;
  const unsigned short* Vp = VTd + (size_t)bh * HD * T_LEN;

  // LDS: double-buffered K,V tiles (swizzled) + per-wave P transpose buffer
  __shared__ unsigned short kv[2][2][4096];    // [buf][K/V][row][64]
  __shared__ unsigned short plds[4][16][64];   // swizzled

  v8bf qf0 = *(const v8bf*)(Qp + (qrow0 + r) * HD + g * 8);
  v8bf qf1 = *(const v8bf*)(Qp + (qrow0 + r) * HD + 32 + g * 8);

  v4f zero = {0.f, 0.f, 0.f, 0.f};
  v4f oacc[4];
#pragma unroll
  for (int i = 0; i < 4; ++i) oacc[i] = zero;
  float mi[4] = {-1e30f, -1e30f, -1e30f, -1e30f};
  float li[4] = {0.f, 0.f, 0.f, 0.f};

  int ktiles = qt + 2; if (ktiles > 32) ktiles = 32;

  // stage K and V tile kt into buffer b. LDS dest linear; global src
  // pre-swizzled: chunk c (16B) of row holds global chunk c ^ (row&7).
  auto stage = [&](int b, int kt) {
    int j0 = kt * 64;
    const unsigned short* Kt = Kp + (size_t)j0 * HD;   // contiguous 8KB
#pragma unroll
    for (int is = 0; is < 2; ++is) {
      int q = is * 256 + tid;
      int row = q >> 3, c = q & 7;
      int swc = (c ^ (row & 7)) << 3;                  // swizzled chunk, shorts
      __builtin_amdgcn_global_load_lds(
          (const __attribute__((address_space(1))) void*)(Kt + row * 64 + swc),
          (__attribute__((address_space(3))) void*)(&kv[b][0][0] + is * 2048 + wave * 512),
          16, 0, 0);
      __builtin_amdgcn_global_load_lds(
          (const __attribute__((address_space(1))) void*)(Vp + (size_t)row * T_LEN + j0 + swc),
          (__attribute__((address_space(3))) void*)(&kv[b][1][0] + is * 2048 + wave * 512),
          16, 0, 0);
    }
  };

  stage(0, 0);
  asm volatile("s_waitcnt vmcnt(0)");
  __syncthreads();
  int cur = 0;

  for (int kt = 0; kt < ktiles; ++kt) {
    if (kt + 1 < ktiles) stage(cur ^ 1, kt + 1);
    int j0 = kt * 64;
    const unsigned short* kb = &kv[cur][0][0];
    const unsigned short* vb = &kv[cur][1][0];
    int sw = r & 7;
    v4f s[4];
#pragma unroll
    for (int nt = 0; nt < 4; ++nt) {
      int krow = (nt * 16 + r) * 64;
      v8bf b0 = *(const v8bf*)(kb + krow + ((g ^ sw) << 3));
      v8bf b1 = *(const v8bf*)(kb + krow + (((g + 4) ^ sw) << 3));
      v4f a = zero;
      a = __builtin_amdgcn_mfma_f32_16x16x32_bf16(qf0, b0, a, 0, 0, 0);
      a = __builtin_amdgcn_mfma_f32_16x16x32_bf16(qf1, b1, a, 0, 0, 0);
      s[nt] = a;
    }
    if (j0 + 63 > qrow0 + 64) {   // only boundary tiles need the mask
#pragma unroll
      for (int nt = 0; nt < 4; ++nt)
#pragma unroll
        for (int rg = 0; rg < 4; ++rg) {
          int qi = qrow0 + g * 4 + rg;
          int kj = j0 + nt * 16 + r;
          if (kj > qi + 64) s[nt][rg] = -1e30f;
        }
    }
    float pm[4], al[4], rs[4];
#pragma unroll
    for (int rg = 0; rg < 4; ++rg)
      pm[rg] = fmaxf(fmaxf(s[0][rg], s[1][rg]), fmaxf(s[2][rg], s[3][rg]));
#pragma unroll
    for (int off = 1; off < 16; off <<= 1)
#pragma unroll
      for (int rg = 0; rg < 4; ++rg)
        pm[rg] = fmaxf(pm[rg], __shfl_xor(pm[rg], off, 64));
#pragma unroll
    for (int rg = 0; rg < 4; ++rg) {
      float mn = fmaxf(mi[rg], pm[rg]);
      al[rg] = __expf(mi[rg] - mn);
      mi[rg] = mn;
      rs[rg] = 0.f;
    }
#pragma unroll
    for (int nt = 0; nt < 4; ++nt)
#pragma unroll
      for (int rg = 0; rg < 4; ++rg) {
        float p = __expf(s[nt][rg] - mi[rg]);
        s[nt][rg] = p;
        rs[rg] += p;
      }
#pragma unroll
    for (int off = 1; off < 16; off <<= 1)
#pragma unroll
      for (int rg = 0; rg < 4; ++rg)
        rs[rg] += __shfl_xor(rs[rg], off, 64);
#pragma unroll
    for (int rg = 0; rg < 4; ++rg)
      li[rg] = li[rg] * al[rg] + rs[rg];
#pragma unroll
    for (int nt = 0; nt < 4; ++nt)
#pragma unroll
      for (int rg = 0; rg < 4; ++rg)
        oacc[nt][rg] *= al[rg];
    // transpose P (C-layout) -> A-layout via per-wave swizzled LDS
    unsigned short* pl = &plds[wave][0][0];
#pragma unroll
    for (int nt = 0; nt < 4; ++nt)
#pragma unroll
      for (int rg = 0; rg < 4; ++rg) {
        int prow = g * 4 + rg;
        int pcol = nt * 16 + r;
        int pc = (pcol >> 3) ^ (prow & 7);
        pl[prow * 64 + pc * 8 + (pcol & 7)] = f2bf(s[nt][rg]);
      }
    int swp = r & 7;
    v8bf pa0 = *(const v8bf*)(pl + r * 64 + ((g ^ swp) << 3));
    v8bf pa1 = *(const v8bf*)(pl + r * 64 + (((g + 4) ^ swp) << 3));
#pragma unroll
    for (int nt = 0; nt < 4; ++nt) {
      int vrow = (nt * 16 + r) * 64;
      v8bf v0 = *(const v8bf*)(vb + vrow + ((g ^ sw) << 3));
      v8bf v1 = *(const v8bf*)(vb + vrow + (((g + 4) ^ sw) << 3));
      oacc[nt] = __builtin_amdgcn_mfma_f32_16x16x32_bf16(pa0, v0, oacc[nt], 0, 0, 0);
      oacc[nt] = __builtin_amdgcn_mfma_f32_16x16x32_bf16(pa1, v1, oacc[nt], 0, 0, 0);
    }
    asm volatile("s_waitcnt vmcnt(0)");
    __syncthreads();
    cur ^= 1;
  }
#pragma unroll
  for (int rg = 0; rg < 4; ++rg) li[rg] = 1.0f / li[rg];
#pragma unroll
  for (int nt = 0; nt < 4; ++nt)
#pragma unroll
    for (int rg = 0; rg < 4; ++rg)
      Od[((size_t)bh * T_LEN + qrow0 + g * 4 + rg) * HD + nt * 16 + r] =
          f2bf(oacc[nt][rg] * li[rg]);
}

// ---------------- output projection: out = O @ wp^T (fp32 out) ----------------
__global__ __launch_bounds__(256) void proj_gemm(
    const unsigned short* __restrict__ Ob, const unsigned short* __restrict__ Wpb,
    float* __restrict__ out) {
  __shared__ unsigned short lds[8192];
  int tid = threadIdx.x;
  int wave = tid >> 6, lane = tid & 63;
  int wm = wave >> 1, wn = wave & 1;
  int r = lane & 15, g = lane >> 4;
  int m0 = blockIdx.y * 128, n0 = blockIdx.x * 128;

  v4f zero = {0.f, 0.f, 0.f, 0.f};
  v4f acc[4][4];
#pragma unroll
  for (int i = 0; i < 4; ++i)
#pragma unroll
    for (int j = 0; j < 4; ++j) acc[i][j] = zero;

  for (int k0 = 0; k0 < 1024; k0 += 32) {
#pragma unroll
    for (int it = 0; it < 2; ++it) {
      int c = it * 256 + tid;
      int row = m0 + (c >> 2);
      int b = row >> 11, t = row & 2047;
      int k = k0 + (c & 3) * 8;
      int h = k >> 6, d = k & 63;
      __builtin_amdgcn_global_load_lds(
          (const __attribute__((address_space(1))) void*)(Ob + (((size_t)(b * NH + h)) * T_LEN + t) * HD + d),
          (__attribute__((address_space(3))) void*)(lds + it * 2048 + wave * 512),
          16, 0, 0);
      __builtin_amdgcn_global_load_lds(
          (const __attribute__((address_space(1))) void*)(Wpb + (size_t)(n0 + (c >> 2)) * 1024 + k0 + (c & 3) * 8),
          (__attribute__((address_space(3))) void*)(lds + 4096 + it * 2048 + wave * 512),
          16, 0, 0);
    }
    __syncthreads();
    v8bf af[4], bfr[4];
#pragma unroll
    for (int mf = 0; mf < 4; ++mf)
      af[mf] = *(const v8bf*)(lds + (wm * 64 + mf * 16 + r) * 32 + g * 8);
#pragma unroll
    for (int nf = 0; nf < 4; ++nf)
      bfr[nf] = *(const v8bf*)(lds + 4096 + (wn * 64 + nf * 16 + r) * 32 + g * 8);
#pragma unroll
    for (int mf = 0; mf < 4; ++mf)
#pragma unroll
      for (int nf = 0; nf < 4; ++nf)
        acc[mf][nf] = __builtin_amdgcn_mfma_f32_16x16x32_bf16(af[mf], bfr[nf], acc[mf][nf], 0, 0, 0);
    __syncthreads();
  }
#pragma unroll
  for (int mf = 0; mf < 4; ++mf)
#pragma unroll
    for (int nf = 0; nf < 4; ++nf) {
      int col = n0 + wn * 64 + nf * 16 + r;
      int row0 = m0 + wm * 64 + mf * 16 + g * 4;
#pragma unroll
      for (int rg = 0; rg < 4; ++rg)
        out[(size_t)(row0 + rg) * 1024 + col] = acc[mf][nf][rg];
    }
}

extern "C" void kernel_launch(void* const* d_in, const int* in_sizes, int n_in,
                              void* d_out, int out_size, void* d_ws, size_t ws_size,
                              hipStream_t stream) {
  const float* x1 = (const float*)d_in[0];
  const float* x2 = (const float*)d_in[1];
  const float* wq = (const float*)d_in[2];
  const float* bq = (const float*)d_in[3];
  const float* wk = (const float*)d_in[4];
  const float* bk = (const float*)d_in[5];
  const float* wv = (const float*)d_in[6];
  const float* bv = (const float*)d_in[7];
  const float* wp = (const float*)d_in[8];
  float* out = (float*)d_out;
  char* ws = (char*)d_ws;

  unsigned short* x1b = (unsigned short*)(ws + WS_X1B);
  unsigned short* x2b = (unsigned short*)(ws + WS_X2B);
  unsigned short* wqb = (unsigned short*)(ws + WS_W);
  unsigned short* wpb = wqb + 3 * 1048576;
  float* ctab = (float*)(ws + WS_CTAB);
  float* stab = (float*)(ws + WS_STAB);
  unsigned short* Qd = (unsigned short*)(ws + WS_Q);
  unsigned short* Kd = (unsigned short*)(ws + WS_K);
  unsigned short* VTd = (unsigned short*)(ws + WS_VT);
  unsigned short* Od = (unsigned short*)(ws + WS_O);

  cvt_kernel<<<12288, 256, 0, stream>>>(x1, x2, wq, wk, wv, wp, x1b, x2b, wqb);
  tab_kernel<<<256, 256, 0, stream>>>(ctab, stab);
  qkv_gemm<<<dim3(8, 32, 3), 256, 0, stream>>>(x1b, x2b, wqb, bq, bk, bv, Qd, Kd, VTd);
  rope_kernel<<<4096, 256, 0, stream>>>(Qd, Kd, ctab, stab);
  attn_kernel<<<dim3(32, 32), 256, 0, stream>>>(Qd, Kd, VTd, Od);
  proj_gemm<<<dim3(8, 32), 256, 0, stream>>>(Od, wpb, out);
}

// Round 3
// 186.100 us; speedup vs baseline: 2.0864x; 1.1316x over previous
//
#include <hip/hip_runtime.h>
#include <hip/hip_bf16.h>

typedef __bf16 v8bf __attribute__((ext_vector_type(8)));
typedef float  v4f  __attribute__((ext_vector_type(4)));
typedef unsigned int u32x4 __attribute__((ext_vector_type(4)));

#define T_LEN 2048
#define NH 16
#define HD 64
#define BH 32
#define C_DIM 1024

// workspace byte offsets
#define WS_X1B  ((size_t)0)
#define WS_X2B  ((size_t)8  << 20)
#define WS_W    ((size_t)16 << 20)   // wq,wk,wv,wp bf16, 2MB each
#define WS_CTAB ((size_t)24 << 20)
#define WS_STAB (WS_CTAB + 262144)
#define WS_Q    ((size_t)25 << 20)
#define WS_K    ((size_t)33 << 20)
#define WS_VT   ((size_t)41 << 20)
#define WS_O    ((size_t)0)          // overlaps X1B (dead by then)

__device__ __forceinline__ unsigned short f2bf(float f) {
  unsigned int u = __float_as_uint(f);
  u += 0x7fffu + ((u >> 16) & 1u);
  return (unsigned short)(u >> 16);
}
__device__ __forceinline__ float bf2f(unsigned short h) {
  return __uint_as_float(((unsigned int)h) << 16);
}

// DPP cross-lane (VALU pipe, not LDS): butterfly within 16-lane rows
template <int CTRL>
__device__ __forceinline__ float dpp_maxstep(float x) {
  int y = __builtin_amdgcn_mov_dpp(__float_as_int(x), CTRL, 0xF, 0xF, true);
  return fmaxf(x, __int_as_float(y));
}
__device__ __forceinline__ float dpp_xor1(float x) {
  int y = __builtin_amdgcn_mov_dpp(__float_as_int(x), 0xB1, 0xF, 0xF, true);
  return __int_as_float(y);
}

// ---------------- fp32 -> bf16 conversion (x1, x2, wq, wk, wv, wp) -------------
__global__ __launch_bounds__(256) void cvt_kernel(
    const float* __restrict__ x1, const float* __restrict__ x2,
    const float* __restrict__ wq, const float* __restrict__ wk,
    const float* __restrict__ wv, const float* __restrict__ wp,
    unsigned short* __restrict__ x1b, unsigned short* __restrict__ x2b,
    unsigned short* __restrict__ wqb) {
  int i = blockIdx.x * 256 + threadIdx.x;   // float4 index, total 3M
  if (i >= 3145728) return;
  const float* s; unsigned short* d; int off;
  if (i < 1048576) { s = x1; d = x1b; off = i; }
  else if (i < 2097152) { s = x2; d = x2b; off = i - 1048576; }
  else {
    int j = i - 2097152;
    int w = j >> 18;            // 0..3 (wq,wk,wv,wp: 256K float4 each)
    off = j & 262143;
    s = (w == 0) ? wq : (w == 1) ? wk : (w == 2) ? wv : wp;
    d = wqb + ((size_t)w * 1048576);
  }
  float4 v = ((const float4*)s)[off];
  ushort4 o;
  o.x = f2bf(v.x); o.y = f2bf(v.y); o.z = f2bf(v.z); o.w = f2bf(v.w);
  ((ushort4*)d)[off] = o;
}

// ---------------- RoPE tables ----------------
__global__ __launch_bounds__(256) void tab_kernel(float* __restrict__ ctab,
                                                  float* __restrict__ stab) {
  int i = blockIdx.x * 256 + threadIdx.x;   // 65536 = 2048*32
  int t = i >> 5, f = i & 31;
  float freq = powf(10000.0f, -(float)f * (1.0f / 32.0f));
  float a = (float)t * freq;
  ctab[i] = cosf(a);
  stab[i] = sinf(a);
}

// ---------------- QKV GEMM + bias + fused RoPE -----------------
// z=0: Q <- rope(x1*wq^T+bq)*0.125 -> [bh][t][d] bf16
// z=1: K <- rope(x2*wk^T+bk)       -> [bh][t][d] bf16
// z=2: V -> stored transposed [bh][d][t] bf16
__global__ __launch_bounds__(256) void qkv_gemm(
    const unsigned short* __restrict__ x1b, const unsigned short* __restrict__ x2b,
    const unsigned short* __restrict__ wall,
    const float* __restrict__ bq, const float* __restrict__ bk,
    const float* __restrict__ bv,
    const float* __restrict__ ctab, const float* __restrict__ stab,
    unsigned short* __restrict__ Qd, unsigned short* __restrict__ Kd,
    unsigned short* __restrict__ VTd) {
  int z = blockIdx.z;
  const unsigned short* A = (z == 0) ? x1b : x2b;
  const unsigned short* W = wall + (size_t)z * 1048576;
  const float* bias = (z == 0) ? bq : (z == 1) ? bk : bv;

  __shared__ unsigned short lds[8192];   // A tile [128][32] @0, B tile @4096
  int tid = threadIdx.x;
  int wave = tid >> 6, lane = tid & 63;
  int wm = wave >> 1, wn = wave & 1;
  int r = lane & 15, g = lane >> 4;
  int m0 = blockIdx.y * 128, n0 = blockIdx.x * 128;

  v4f zero = {0.f, 0.f, 0.f, 0.f};
  v4f acc[4][4];
#pragma unroll
  for (int i = 0; i < 4; ++i)
#pragma unroll
    for (int j = 0; j < 4; ++j) acc[i][j] = zero;

  for (int k0 = 0; k0 < 1024; k0 += 32) {
    const unsigned short* Ab = A + (size_t)m0 * 1024 + k0;
    const unsigned short* Bb = W + (size_t)n0 * 1024 + k0;
#pragma unroll
    for (int it = 0; it < 2; ++it) {
      int c = it * 256 + tid;
      __builtin_amdgcn_global_load_lds(
          (const __attribute__((address_space(1))) void*)(Ab + (size_t)(c >> 2) * 1024 + (c & 3) * 8),
          (__attribute__((address_space(3))) void*)(lds + it * 2048 + wave * 512),
          16, 0, 0);
      __builtin_amdgcn_global_load_lds(
          (const __attribute__((address_space(1))) void*)(Bb + (size_t)(c >> 2) * 1024 + (c & 3) * 8),
          (__attribute__((address_space(3))) void*)(lds + 4096 + it * 2048 + wave * 512),
          16, 0, 0);
    }
    __syncthreads();
    v8bf af[4], bfr[4];
#pragma unroll
    for (int mf = 0; mf < 4; ++mf)
      af[mf] = *(const v8bf*)(lds + (wm * 64 + mf * 16 + r) * 32 + g * 8);
#pragma unroll
    for (int nf = 0; nf < 4; ++nf)
      bfr[nf] = *(const v8bf*)(lds + 4096 + (wn * 64 + nf * 16 + r) * 32 + g * 8);
#pragma unroll
    for (int mf = 0; mf < 4; ++mf)
#pragma unroll
      for (int nf = 0; nf < 4; ++nf)
        acc[mf][nf] = __builtin_amdgcn_mfma_f32_16x16x32_bf16(af[mf], bfr[nf], acc[mf][nf], 0, 0, 0);
    __syncthreads();
  }

#pragma unroll
  for (int nf = 0; nf < 4; ++nf) {
    int col = n0 + wn * 64 + nf * 16 + r;
    float bv_ = bias[col];
    int h = col >> 6, d = col & 63;
    int f = d >> 1;
    float sgn = (d & 1) ? 1.0f : -1.0f;
#pragma unroll
    for (int mf = 0; mf < 4; ++mf) {
      int row0 = m0 + wm * 64 + mf * 16 + g * 4;
      int b = row0 >> 11, t0 = row0 & 2047;
      if (z < 2) {
        unsigned short* dst = (z == 0) ? Qd : Kd;
        float scale = (z == 0) ? 0.125f : 1.0f;   // fold D^-1/2 into Q
#pragma unroll
        for (int rg = 0; rg < 4; ++rg) {
          float own = acc[mf][nf][rg] + bv_;
          float prt = dpp_xor1(own);              // partner of the (x0,x1) pair
          float cv = ctab[(t0 + rg) * 32 + f];
          float sv = stab[(t0 + rg) * 32 + f];
          float o = (own * cv + sgn * prt * sv) * scale;
          dst[(((size_t)(b * NH + h)) * T_LEN + t0 + rg) * HD + d] = f2bf(o);
        }
      } else {
        ushort4 pk;
        pk.x = f2bf(acc[mf][nf][0] + bv_);
        pk.y = f2bf(acc[mf][nf][1] + bv_);
        pk.z = f2bf(acc[mf][nf][2] + bv_);
        pk.w = f2bf(acc[mf][nf][3] + bv_);
        *(ushort4*)(VTd + (((size_t)(b * NH + h)) * HD + d) * T_LEN + t0) = pk;
      }
    }
  }
}

// ---------------- flash attention, mask j <= i + 64 ----------------
// grid (32 qtiles reversed, 32 bh), 4 waves x 16 q-rows
// K/V staged in LDS (dbuf, swizzled); softmax max via DPP, sum via ones-MFMA.
__global__ __launch_bounds__(256) void attn_kernel(
    const unsigned short* __restrict__ Qd, const unsigned short* __restrict__ Kd,
    const unsigned short* __restrict__ VTd, unsigned short* __restrict__ Od) {
  int bh = blockIdx.y;
  int qt = (int)gridDim.x - 1 - (int)blockIdx.x;  // heavy tiles first
  int q0 = qt * 64;
  int tid = threadIdx.x, wave = tid >> 6, lane = tid & 63;
  int r = lane & 15, g = lane >> 4;
  int qrow0 = q0 + wave * 16;
  const unsigned short* Qp = Qd + (size_t)bh * T_LEN * HD;
  const unsigned short* Kp = Kd + (size_t)bh * T_LEN * HD;
  const unsigned short* Vp = VTd + (size_t)bh * HD * T_LEN;

  __shared__ unsigned short kv[2][2][4096];    // [buf][K/V][row][64] swizzled
  __shared__ unsigned short plds[4][16][64];   // per-wave P transpose, swizzled

  v8bf qf0 = *(const v8bf*)(Qp + (qrow0 + r) * HD + g * 8);
  v8bf qf1 = *(const v8bf*)(Qp + (qrow0 + r) * HD + 32 + g * 8);

  // ones B-fragment: row 0 (lanes r==0) = 1.0, else 0  -> l accumulator column
  u32x4 ow = (r == 0) ? (u32x4)0x3F803F80u : (u32x4)0u;
  v8bf onesf = *(v8bf*)&ow;

  v4f zero = {0.f, 0.f, 0.f, 0.f};
  v4f oacc[4];
#pragma unroll
  for (int i = 0; i < 4; ++i) oacc[i] = zero;
  v4f lacc = zero;
  float mi[4] = {-1e30f, -1e30f, -1e30f, -1e30f};

  int ktiles = qt + 2; if (ktiles > 32) ktiles = 32;

  auto stage = [&](int b, int kt) {
    int j0 = kt * 64;
    const unsigned short* Kt = Kp + (size_t)j0 * HD;   // contiguous 8KB
#pragma unroll
    for (int is = 0; is < 2; ++is) {
      int q = is * 256 + tid;
      int row = q >> 3, c = q & 7;
      int swc = (c ^ (row & 7)) << 3;                  // swizzled chunk, shorts
      __builtin_amdgcn_global_load_lds(
          (const __attribute__((address_space(1))) void*)(Kt + row * 64 + swc),
          (__attribute__((address_space(3))) void*)(&kv[b][0][0] + is * 2048 + wave * 512),
          16, 0, 0);
      __builtin_amdgcn_global_load_lds(
          (const __attribute__((address_space(1))) void*)(Vp + (size_t)row * T_LEN + j0 + swc),
          (__attribute__((address_space(3))) void*)(&kv[b][1][0] + is * 2048 + wave * 512),
          16, 0, 0);
    }
  };

  stage(0, 0);
  asm volatile("s_waitcnt vmcnt(0)");
  __syncthreads();
  int cur = 0;

  for (int kt = 0; kt < ktiles; ++kt) {
    if (kt + 1 < ktiles) stage(cur ^ 1, kt + 1);
    int j0 = kt * 64;
    const unsigned short* kb = &kv[cur][0][0];
    const unsigned short* vb = &kv[cur][1][0];
    int sw = r & 7;
    v4f s[4];
#pragma unroll
    for (int nt = 0; nt < 4; ++nt) {
      int krow = (nt * 16 + r) * 64;
      v8bf b0 = *(const v8bf*)(kb + krow + ((g ^ sw) << 3));
      v8bf b1 = *(const v8bf*)(kb + krow + (((g + 4) ^ sw) << 3));
      v4f a = zero;
      a = __builtin_amdgcn_mfma_f32_16x16x32_bf16(qf0, b0, a, 0, 0, 0);
      a = __builtin_amdgcn_mfma_f32_16x16x32_bf16(qf1, b1, a, 0, 0, 0);
      s[nt] = a;
    }
    if (j0 + 63 > qrow0 + 64) {   // only boundary tiles need the mask
#pragma unroll
      for (int nt = 0; nt < 4; ++nt)
#pragma unroll
        for (int rg = 0; rg < 4; ++rg) {
          int qi = qrow0 + g * 4 + rg;
          int kj = j0 + nt * 16 + r;
          if (kj > qi + 64) s[nt][rg] = -1e30f;
        }
    }
    float pm[4], al[4];
#pragma unroll
    for (int rg = 0; rg < 4; ++rg) {
      float m = fmaxf(fmaxf(s[0][rg], s[1][rg]), fmaxf(s[2][rg], s[3][rg]));
      m = dpp_maxstep<0xB1>(m);     // xor 1
      m = dpp_maxstep<0x4E>(m);     // xor 2
      m = dpp_maxstep<0x141>(m);    // xor 4 (row_half_mirror)
      m = dpp_maxstep<0x140>(m);    // xor 8 (row_mirror)
      pm[rg] = m;
    }
#pragma unroll
    for (int rg = 0; rg < 4; ++rg) {
      float mn = fmaxf(mi[rg], pm[rg]);
      al[rg] = __expf(mi[rg] - mn);
      mi[rg] = mn;
    }
#pragma unroll
    for (int nt = 0; nt < 4; ++nt)
#pragma unroll
      for (int rg = 0; rg < 4; ++rg)
        s[nt][rg] = __expf(s[nt][rg] - mi[rg]);
#pragma unroll
    for (int nt = 0; nt < 4; ++nt)
#pragma unroll
      for (int rg = 0; rg < 4; ++rg)
        oacc[nt][rg] *= al[rg];
#pragma unroll
    for (int rg = 0; rg < 4; ++rg) lacc[rg] *= al[rg];
    // transpose P (C-layout) -> A-layout via per-wave swizzled LDS
    unsigned short* pl = &plds[wave][0][0];
#pragma unroll
    for (int nt = 0; nt < 4; ++nt)
#pragma unroll
      for (int rg = 0; rg < 4; ++rg) {
        int prow = g * 4 + rg;
        int pcol = nt * 16 + r;
        int pc = (pcol >> 3) ^ (prow & 7);
        pl[prow * 64 + pc * 8 + (pcol & 7)] = f2bf(s[nt][rg]);
      }
    int swp = r & 7;
    v8bf pa0 = *(const v8bf*)(pl + r * 64 + ((g ^ swp) << 3));
    v8bf pa1 = *(const v8bf*)(pl + r * 64 + (((g + 4) ^ swp) << 3));
#pragma unroll
    for (int nt = 0; nt < 4; ++nt) {
      int vrow = (nt * 16 + r) * 64;
      v8bf v0 = *(const v8bf*)(vb + vrow + ((g ^ sw) << 3));
      v8bf v1 = *(const v8bf*)(vb + vrow + (((g + 4) ^ sw) << 3));
      oacc[nt] = __builtin_amdgcn_mfma_f32_16x16x32_bf16(pa0, v0, oacc[nt], 0, 0, 0);
      oacc[nt] = __builtin_amdgcn_mfma_f32_16x16x32_bf16(pa1, v1, oacc[nt], 0, 0, 0);
    }
    // l-column: sum_k P[row][k] with identical rescale history
    lacc = __builtin_amdgcn_mfma_f32_16x16x32_bf16(pa0, onesf, lacc, 0, 0, 0);
    lacc = __builtin_amdgcn_mfma_f32_16x16x32_bf16(pa1, onesf, lacc, 0, 0, 0);
    asm volatile("s_waitcnt vmcnt(0)");
    __syncthreads();
    cur ^= 1;
  }
  float li[4];
#pragma unroll
  for (int rg = 0; rg < 4; ++rg)
    li[rg] = 1.0f / __shfl(lacc[rg], lane & 48, 64);   // broadcast from r==0
#pragma unroll
  for (int nt = 0; nt < 4; ++nt)
#pragma unroll
    for (int rg = 0; rg < 4; ++rg)
      Od[((size_t)bh * T_LEN + qrow0 + g * 4 + rg) * HD + nt * 16 + r] =
          f2bf(oacc[nt][rg] * li[rg]);
}

// ---------------- output projection: out = O @ wp^T (fp32 out) ----------------
__global__ __launch_bounds__(256) void proj_gemm(
    const unsigned short* __restrict__ Ob, const unsigned short* __restrict__ Wpb,
    float* __restrict__ out) {
  __shared__ unsigned short lds[8192];
  int tid = threadIdx.x;
  int wave = tid >> 6, lane = tid & 63;
  int wm = wave >> 1, wn = wave & 1;
  int r = lane & 15, g = lane >> 4;
  int m0 = blockIdx.y * 128, n0 = blockIdx.x * 128;

  v4f zero = {0.f, 0.f, 0.f, 0.f};
  v4f acc[4][4];
#pragma unroll
  for (int i = 0; i < 4; ++i)
#pragma unroll
    for (int j = 0; j < 4; ++j) acc[i][j] = zero;

  for (int k0 = 0; k0 < 1024; k0 += 32) {
#pragma unroll
    for (int it = 0; it < 2; ++it) {
      int c = it * 256 + tid;
      int row = m0 + (c >> 2);
      int b = row >> 11, t = row & 2047;
      int k = k0 + (c & 3) * 8;
      int h = k >> 6, d = k & 63;
      __builtin_amdgcn_global_load_lds(
          (const __attribute__((address_space(1))) void*)(Ob + (((size_t)(b * NH + h)) * T_LEN + t) * HD + d),
          (__attribute__((address_space(3))) void*)(lds + it * 2048 + wave * 512),
          16, 0, 0);
      __builtin_amdgcn_global_load_lds(
          (const __attribute__((address_space(1))) void*)(Wpb + (size_t)(n0 + (c >> 2)) * 1024 + k0 + (c & 3) * 8),
          (__attribute__((address_space(3))) void*)(lds + 4096 + it * 2048 + wave * 512),
          16, 0, 0);
    }
    __syncthreads();
    v8bf af[4], bfr[4];
#pragma unroll
    for (int mf = 0; mf < 4; ++mf)
      af[mf] = *(const v8bf*)(lds + (wm * 64 + mf * 16 + r) * 32 + g * 8);
#pragma unroll
    for (int nf = 0; nf < 4; ++nf)
      bfr[nf] = *(const v8bf*)(lds + 4096 + (wn * 64 + nf * 16 + r) * 32 + g * 8);
#pragma unroll
    for (int mf = 0; mf < 4; ++mf)
#pragma unroll
      for (int nf = 0; nf < 4; ++nf)
        acc[mf][nf] = __builtin_amdgcn_mfma_f32_16x16x32_bf16(af[mf], bfr[nf], acc[mf][nf], 0, 0, 0);
    __syncthreads();
  }
#pragma unroll
  for (int mf = 0; mf < 4; ++mf)
#pragma unroll
    for (int nf = 0; nf < 4; ++nf) {
      int col = n0 + wn * 64 + nf * 16 + r;
      int row0 = m0 + wm * 64 + mf * 16 + g * 4;
#pragma unroll
      for (int rg = 0; rg < 4; ++rg)
        out[(size_t)(row0 + rg) * 1024 + col] = acc[mf][nf][rg];
    }
}

extern "C" void kernel_launch(void* const* d_in, const int* in_sizes, int n_in,
                              void* d_out, int out_size, void* d_ws, size_t ws_size,
                              hipStream_t stream) {
  const float* x1 = (const float*)d_in[0];
  const float* x2 = (const float*)d_in[1];
  const float* wq = (const float*)d_in[2];
  const float* bq = (const float*)d_in[3];
  const float* wk = (const float*)d_in[4];
  const float* bk = (const float*)d_in[5];
  const float* wv = (const float*)d_in[6];
  const float* bv = (const float*)d_in[7];
  const float* wp = (const float*)d_in[8];
  float* out = (float*)d_out;
  char* ws = (char*)d_ws;

  unsigned short* x1b = (unsigned short*)(ws + WS_X1B);
  unsigned short* x2b = (unsigned short*)(ws + WS_X2B);
  unsigned short* wqb = (unsigned short*)(ws + WS_W);
  unsigned short* wpb = wqb + 3 * 1048576;
  float* ctab = (float*)(ws + WS_CTAB);
  float* stab = (float*)(ws + WS_STAB);
  unsigned short* Qd = (unsigned short*)(ws + WS_Q);
  unsigned short* Kd = (unsigned short*)(ws + WS_K);
  unsigned short* VTd = (unsigned short*)(ws + WS_VT);
  unsigned short* Od = (unsigned short*)(ws + WS_O);

  cvt_kernel<<<12288, 256, 0, stream>>>(x1, x2, wq, wk, wv, wp, x1b, x2b, wqb);
  tab_kernel<<<256, 256, 0, stream>>>(ctab, stab);
  qkv_gemm<<<dim3(8, 32, 3), 256, 0, stream>>>(x1b, x2b, wqb, bq, bk, bv, ctab, stab, Qd, Kd, VTd);
  attn_kernel<<<dim3(32, 32), 256, 0, stream>>>(Qd, Kd, VTd, Od);
  proj_gemm<<<dim3(8, 32), 256, 0, stream>>>(Od, wpb, out);
}

// Round 7
// 160.224 us; speedup vs baseline: 2.4234x; 1.1615x over previous
//
#include <hip/hip_runtime.h>
#include <hip/hip_bf16.h>

typedef __bf16 v8bf __attribute__((ext_vector_type(8)));
typedef float  v4f  __attribute__((ext_vector_type(4)));

#define T_LEN 2048
#define NH 16
#define HD 64
#define BH 32
#define C_DIM 1024

// workspace byte offsets
#define WS_X1B  ((size_t)0)
#define WS_X2B  ((size_t)8  << 20)
#define WS_W    ((size_t)16 << 20)   // wq,wk,wv,wp bf16, 2MB each
#define WS_CTAB ((size_t)24 << 20)
#define WS_STAB (WS_CTAB + 262144)
#define WS_Q    ((size_t)25 << 20)
#define WS_K    ((size_t)33 << 20)
#define WS_VT   ((size_t)41 << 20)
#define WS_O    ((size_t)0)          // overlaps X1B (dead by then)

__device__ __forceinline__ unsigned short f2bf(float f) {
  unsigned int u = __float_as_uint(f);
  u += 0x7fffu + ((u >> 16) & 1u);
  return (unsigned short)(u >> 16);
}
__device__ __forceinline__ float bf2f(unsigned short h) {
  return __uint_as_float(((unsigned int)h) << 16);
}

__device__ __forceinline__ float dpp_xor1(float x) {
  int y = __builtin_amdgcn_mov_dpp(__float_as_int(x), 0xB1, 0xF, 0xF, true);
  return __int_as_float(y);
}

// cross-g (lanes r, r+16, r+32, r+48) reductions via compiler-lowered shuffles
// (known-good; exotic primitives removed for bisection)
__device__ __forceinline__ float xg_max(float m) {
  m = fmaxf(m, __shfl_xor(m, 16, 64));
  m = fmaxf(m, __shfl_xor(m, 32, 64));
  return m;
}
__device__ __forceinline__ float xg_sum(float m) {
  m = m + __shfl_xor(m, 16, 64);
  m = m + __shfl_xor(m, 32, 64);
  return m;
}
__device__ __forceinline__ unsigned int packbf2(float lo, float hi) {
  return (unsigned int)f2bf(lo) | ((unsigned int)f2bf(hi) << 16);
}

// ---------------- fp32 -> bf16 conversion (x1, x2, wq, wk, wv, wp) -------------
__global__ __launch_bounds__(256) void cvt_kernel(
    const float* __restrict__ x1, const float* __restrict__ x2,
    const float* __restrict__ wq, const float* __restrict__ wk,
    const float* __restrict__ wv, const float* __restrict__ wp,
    unsigned short* __restrict__ x1b, unsigned short* __restrict__ x2b,
    unsigned short* __restrict__ wqb) {
  int i = blockIdx.x * 256 + threadIdx.x;   // float4 index, total 3M
  if (i >= 3145728) return;
  const float* s; unsigned short* d; int off;
  if (i < 1048576) { s = x1; d = x1b; off = i; }
  else if (i < 2097152) { s = x2; d = x2b; off = i - 1048576; }
  else {
    int j = i - 2097152;
    int w = j >> 18;            // 0..3 (wq,wk,wv,wp: 256K float4 each)
    off = j & 262143;
    s = (w == 0) ? wq : (w == 1) ? wk : (w == 2) ? wv : wp;
    d = wqb + ((size_t)w * 1048576);
  }
  float4 v = ((const float4*)s)[off];
  ushort4 o;
  o.x = f2bf(v.x); o.y = f2bf(v.y); o.z = f2bf(v.z); o.w = f2bf(v.w);
  ((ushort4*)d)[off] = o;
}

// ---------------- RoPE tables ----------------
__global__ __launch_bounds__(256) void tab_kernel(float* __restrict__ ctab,
                                                  float* __restrict__ stab) {
  int i = blockIdx.x * 256 + threadIdx.x;   // 65536 = 2048*32
  int t = i >> 5, f = i & 31;
  float freq = powf(10000.0f, -(float)f * (1.0f / 32.0f));
  float a = (float)t * freq;
  ctab[i] = cosf(a);
  stab[i] = sinf(a);
}

// ---------------- QKV GEMM + bias + fused RoPE -----------------
// z=0: Q <- rope(x1*wq^T+bq)*0.125 -> [bh][t][d] bf16
// z=1: K <- rope(x2*wk^T+bk)       -> [bh][t][d] bf16
// z=2: V -> stored transposed [bh][d][t] bf16
__global__ __launch_bounds__(256) void qkv_gemm(
    const unsigned short* __restrict__ x1b, const unsigned short* __restrict__ x2b,
    const unsigned short* __restrict__ wall,
    const float* __restrict__ bq, const float* __restrict__ bk,
    const float* __restrict__ bv,
    const float* __restrict__ ctab, const float* __restrict__ stab,
    unsigned short* __restrict__ Qd, unsigned short* __restrict__ Kd,
    unsigned short* __restrict__ VTd) {
  int z = blockIdx.z;
  const unsigned short* A = (z == 0) ? x1b : x2b;
  const unsigned short* W = wall + (size_t)z * 1048576;
  const float* bias = (z == 0) ? bq : (z == 1) ? bk : bv;

  __shared__ unsigned short lds[8192];   // A tile [128][32] @0, B tile @4096
  int tid = threadIdx.x;
  int wave = tid >> 6, lane = tid & 63;
  int wm = wave >> 1, wn = wave & 1;
  int r = lane & 15, g = lane >> 4;
  int m0 = blockIdx.y * 128, n0 = blockIdx.x * 128;

  v4f zero = {0.f, 0.f, 0.f, 0.f};
  v4f acc[4][4];
#pragma unroll
  for (int i = 0; i < 4; ++i)
#pragma unroll
    for (int j = 0; j < 4; ++j) acc[i][j] = zero;

  for (int k0 = 0; k0 < 1024; k0 += 32) {
    const unsigned short* Ab = A + (size_t)m0 * 1024 + k0;
    const unsigned short* Bb = W + (size_t)n0 * 1024 + k0;
#pragma unroll
    for (int it = 0; it < 2; ++it) {
      int c = it * 256 + tid;
      __builtin_amdgcn_global_load_lds(
          (const __attribute__((address_space(1))) void*)(Ab + (size_t)(c >> 2) * 1024 + (c & 3) * 8),
          (__attribute__((address_space(3))) void*)(lds + it * 2048 + wave * 512),
          16, 0, 0);
      __builtin_amdgcn_global_load_lds(
          (const __attribute__((address_space(1))) void*)(Bb + (size_t)(c >> 2) * 1024 + (c & 3) * 8),
          (__attribute__((address_space(3))) void*)(lds + 4096 + it * 2048 + wave * 512),
          16, 0, 0);
    }
    __syncthreads();
    v8bf af[4], bfr[4];
#pragma unroll
    for (int mf = 0; mf < 4; ++mf)
      af[mf] = *(const v8bf*)(lds + (wm * 64 + mf * 16 + r) * 32 + g * 8);
#pragma unroll
    for (int nf = 0; nf < 4; ++nf)
      bfr[nf] = *(const v8bf*)(lds + 4096 + (wn * 64 + nf * 16 + r) * 32 + g * 8);
#pragma unroll
    for (int mf = 0; mf < 4; ++mf)
#pragma unroll
      for (int nf = 0; nf < 4; ++nf)
        acc[mf][nf] = __builtin_amdgcn_mfma_f32_16x16x32_bf16(af[mf], bfr[nf], acc[mf][nf], 0, 0, 0);
    __syncthreads();
  }

#pragma unroll
  for (int nf = 0; nf < 4; ++nf) {
    int col = n0 + wn * 64 + nf * 16 + r;
    float bv_ = bias[col];
    int h = col >> 6, d = col & 63;
    int f = d >> 1;
    float sgn = (d & 1) ? 1.0f : -1.0f;
#pragma unroll
    for (int mf = 0; mf < 4; ++mf) {
      int row0 = m0 + wm * 64 + mf * 16 + g * 4;
      int b = row0 >> 11, t0 = row0 & 2047;
      if (z < 2) {
        unsigned short* dst = (z == 0) ? Qd : Kd;
        float scale = (z == 0) ? 0.125f : 1.0f;   // fold D^-1/2 into Q
#pragma unroll
        for (int rg = 0; rg < 4; ++rg) {
          float own = acc[mf][nf][rg] + bv_;
          float prt = dpp_xor1(own);              // partner of the (x0,x1) pair
          float cv = ctab[(t0 + rg) * 32 + f];
          float sv = stab[(t0 + rg) * 32 + f];
          float o = (own * cv + sgn * prt * sv) * scale;
          dst[(((size_t)(b * NH + h)) * T_LEN + t0 + rg) * HD + d] = f2bf(o);
        }
      } else {
        ushort4 pk;
        pk.x = f2bf(acc[mf][nf][0] + bv_);
        pk.y = f2bf(acc[mf][nf][1] + bv_);
        pk.z = f2bf(acc[mf][nf][2] + bv_);
        pk.w = f2bf(acc[mf][nf][3] + bv_);
        *(ushort4*)(VTd + (((size_t)(b * NH + h)) * HD + d) * T_LEN + t0) = pk;
      }
    }
  }
}

// ---------------- flash attention, mask j <= i + 64 ----------------
// grid (32 bh, 16 qtiles reversed), 4 waves x 32 q-rows (2 subtiles of 16)
// K/V staged in LDS (dbuf, swizzled). Swapped QK^T (lane owns q-row r):
// in-lane softmax; P -> PV B-fragment via per-wave swizzled LDS
// (8 ds_write_b32 + 2 ds_read_b128 per subtile); swapped PV (O^T layout).
__global__ __launch_bounds__(256, 2) void attn_kernel(
    const unsigned short* __restrict__ Qd, const unsigned short* __restrict__ Kd,
    const unsigned short* __restrict__ VTd, unsigned short* __restrict__ Od) {
  int bh = blockIdx.x;
  int qt = (int)gridDim.y - 1 - (int)blockIdx.y;  // heavy tiles first
  int tid = threadIdx.x, wave = tid >> 6, lane = tid & 63;
  int r = lane & 15, g = lane >> 4;
  int qb = qt * 128 + wave * 32;
  const unsigned short* Qp = Qd + (size_t)bh * T_LEN * HD;
  const unsigned short* Kp = Kd + (size_t)bh * T_LEN * HD;
  const unsigned short* Vp = VTd + (size_t)bh * HD * T_LEN;

  __shared__ unsigned short kv[2][2][4096];    // [buf][K/V][row 64][64] swizzled
  __shared__ unsigned short plds[4][1024];     // per-wave P buffer [q=16][64] swz

  v8bf qf[2][2];
#pragma unroll
  for (int qs = 0; qs < 2; ++qs)
#pragma unroll
    for (int c = 0; c < 2; ++c)
      qf[qs][c] = *(const v8bf*)(Qp + (size_t)(qb + qs * 16 + r) * HD + c * 32 + g * 8);

  v4f zero = {0.f, 0.f, 0.f, 0.f};
  v4f oacc[2][4];
#pragma unroll
  for (int qs = 0; qs < 2; ++qs)
#pragma unroll
    for (int dt = 0; dt < 4; ++dt) oacc[qs][dt] = zero;
  float mi[2] = {-1e30f, -1e30f};
  float li[2] = {0.f, 0.f};

  int ktiles = 2 * qt + 3; if (ktiles > 32) ktiles = 32;

  auto stage = [&](int b, int kt) {
    int j0 = kt * 64;
    const unsigned short* Kt = Kp + (size_t)j0 * HD;   // contiguous 8KB
#pragma unroll
    for (int is = 0; is < 2; ++is) {
      int q = is * 256 + tid;
      int row = q >> 3, c = q & 7;
      int swc = (c ^ (row & 7)) << 3;                  // swizzled chunk, shorts
      __builtin_amdgcn_global_load_lds(
          (const __attribute__((address_space(1))) void*)(Kt + row * 64 + swc),
          (__attribute__((address_space(3))) void*)(&kv[b][0][0] + is * 2048 + wave * 512),
          16, 0, 0);
      __builtin_amdgcn_global_load_lds(
          (const __attribute__((address_space(1))) void*)(Vp + (size_t)row * T_LEN + j0 + swc),
          (__attribute__((address_space(3))) void*)(&kv[b][1][0] + is * 2048 + wave * 512),
          16, 0, 0);
    }
  };

  stage(0, 0);
  asm volatile("s_waitcnt vmcnt(0)");
  __syncthreads();
  int cur = 0;

  unsigned short* plw = &plds[wave][0];
  int s7 = r & 7;
  int s8 = s7 << 3;                              // swizzle, in shorts

  for (int kt = 0; kt < ktiles; ++kt) {
    if (kt + 1 < ktiles) stage(cur ^ 1, kt + 1);
    int j0 = kt * 64;
    const unsigned short* kb = &kv[cur][0][0];
    const unsigned short* vb = &kv[cur][1][0];
    // K and V fragments (shared by both q-subtiles)
    v8bf kf0[4], kf1[4], vf0[4], vf1[4];
#pragma unroll
    for (int nt = 0; nt < 4; ++nt) {
      int row = (nt * 16 + r) * 64;
      kf0[nt] = *(const v8bf*)(kb + row + ((g ^ s7) << 3));
      kf1[nt] = *(const v8bf*)(kb + row + (((4 + g) ^ s7) << 3));
      vf0[nt] = *(const v8bf*)(vb + row + ((g ^ s7) << 3));
      vf1[nt] = *(const v8bf*)(vb + row + (((4 + g) ^ s7) << 3));
    }
#pragma unroll
    for (int qs = 0; qs < 2; ++qs) {
      int qmin = qb + qs * 16;
      if (j0 > qmin + 79) continue;       // subtile fully masked (wave-uniform)
      // swapped QK^T: S[q=r][k = j0 + nt*16 + g*4 + rg]
      v4f s[4];
#pragma unroll
      for (int nt = 0; nt < 4; ++nt) {
        v4f a = zero;
        a = __builtin_amdgcn_mfma_f32_16x16x32_bf16(kf0[nt], qf[qs][0], a, 0, 0, 0);
        a = __builtin_amdgcn_mfma_f32_16x16x32_bf16(kf1[nt], qf[qs][1], a, 0, 0, 0);
        s[nt] = a;
      }
      if (j0 + 63 > qmin + 64) {          // boundary: apply mask k > q + 64
        int qi64 = qmin + r + 64;
#pragma unroll
        for (int nt = 0; nt < 4; ++nt)
#pragma unroll
          for (int rg = 0; rg < 4; ++rg) {
            int kj = j0 + nt * 16 + g * 4 + rg;
            if (kj > qi64) s[nt][rg] = -1e30f;
          }
      }
      // in-lane max over this lane's 16 keys, then cross-group reduce
      float m = s[0][0];
#pragma unroll
      for (int nt = 0; nt < 4; ++nt)
#pragma unroll
        for (int rg = 0; rg < 4; ++rg) m = fmaxf(m, s[nt][rg]);
      m = xg_max(m);
      float mn = fmaxf(mi[qs], m);
      float al = __expf(mi[qs] - mn);
      mi[qs] = mn;
      float rs = 0.f;
#pragma unroll
      for (int nt = 0; nt < 4; ++nt)
#pragma unroll
        for (int rg = 0; rg < 4; ++rg) {
          float p = __expf(s[nt][rg] - mn);
          s[nt][rg] = p;
          rs += p;
        }
      li[qs] = li[qs] * al + rs;
#pragma unroll
      for (int dt = 0; dt < 4; ++dt) oacc[qs][dt] *= al;
      // P -> per-wave LDS (swizzled), then read back as PV B-fragments.
      // write: element pair k=(16nt+4g+2w,+1) at shorts r*64 + ((16nt+4g+2w)^s8)
#pragma unroll
      for (int nt = 0; nt < 4; ++nt)
#pragma unroll
        for (int w = 0; w < 2; ++w)
          *(unsigned int*)(plw + r * 64 + (((nt << 4) + (g << 2) + (w << 1)) ^ s8)) =
              packbf2(s[nt][2 * w], s[nt][2 * w + 1]);
      // read: pb0 word j @ lane(g,r) = P[q=r][k=8g+j]; pb1: k=32+8g+j
      v8bf pb0 = *(const v8bf*)(plw + r * 64 + ((g ^ s7) << 3));
      v8bf pb1 = *(const v8bf*)(plw + r * 64 + (((4 + g) ^ s7) << 3));
      // swapped PV: O^T[d][q=r]
#pragma unroll
      for (int dt = 0; dt < 4; ++dt) {
        oacc[qs][dt] = __builtin_amdgcn_mfma_f32_16x16x32_bf16(vf0[dt], pb0, oacc[qs][dt], 0, 0, 0);
        oacc[qs][dt] = __builtin_amdgcn_mfma_f32_16x16x32_bf16(vf1[dt], pb1, oacc[qs][dt], 0, 0, 0);
      }
    }
    asm volatile("s_waitcnt vmcnt(0)");
    __syncthreads();
    cur ^= 1;
  }
#pragma unroll
  for (int qs = 0; qs < 2; ++qs) {
    float rli = 1.0f / xg_sum(li[qs]);
#pragma unroll
    for (int dt = 0; dt < 4; ++dt) {
      ushort4 pk;
      pk.x = f2bf(oacc[qs][dt][0] * rli);
      pk.y = f2bf(oacc[qs][dt][1] * rli);
      pk.z = f2bf(oacc[qs][dt][2] * rli);
      pk.w = f2bf(oacc[qs][dt][3] * rli);
      *(ushort4*)(Od + ((size_t)bh * T_LEN + qb + qs * 16 + r) * HD + dt * 16 + g * 4) = pk;
    }
  }
}

// ---------------- output projection: out = O @ wp^T (fp32 out) ----------------
__global__ __launch_bounds__(256) void proj_gemm(
    const unsigned short* __restrict__ Ob, const unsigned short* __restrict__ Wpb,
    float* __restrict__ out) {
  __shared__ unsigned short lds[8192];
  int tid = threadIdx.x;
  int wave = tid >> 6, lane = tid & 63;
  int wm = wave >> 1, wn = wave & 1;
  int r = lane & 15, g = lane >> 4;
  int m0 = blockIdx.y * 128, n0 = blockIdx.x * 128;

  v4f zero = {0.f, 0.f, 0.f, 0.f};
  v4f acc[4][4];
#pragma unroll
  for (int i = 0; i < 4; ++i)
#pragma unroll
    for (int j = 0; j < 4; ++j) acc[i][j] = zero;

  for (int k0 = 0; k0 < 1024; k0 += 32) {
#pragma unroll
    for (int it = 0; it < 2; ++it) {
      int c = it * 256 + tid;
      int row = m0 + (c >> 2);
      int b = row >> 11, t = row & 2047;
      int k = k0 + (c & 3) * 8;
      int h = k >> 6, d = k & 63;
      __builtin_amdgcn_global_load_lds(
          (const __attribute__((address_space(1))) void*)(Ob + (((size_t)(b * NH + h)) * T_LEN + t) * HD + d),
          (__attribute__((address_space(3))) void*)(lds + it * 2048 + wave * 512),
          16, 0, 0);
      __builtin_amdgcn_global_load_lds(
          (const __attribute__((address_space(1))) void*)(Wpb + (size_t)(n0 + (c >> 2)) * 1024 + k0 + (c & 3) * 8),
          (__attribute__((address_space(3))) void*)(lds + 4096 + it * 2048 + wave * 512),
          16, 0, 0);
    }
    __syncthreads();
    v8bf af[4], bfr[4];
#pragma unroll
    for (int mf = 0; mf < 4; ++mf)
      af[mf] = *(const v8bf*)(lds + (wm * 64 + mf * 16 + r) * 32 + g * 8);
#pragma unroll
    for (int nf = 0; nf < 4; ++nf)
      bfr[nf] = *(const v8bf*)(lds + 4096 + (wn * 64 + nf * 16 + r) * 32 + g * 8);
#pragma unroll
    for (int mf = 0; mf < 4; ++mf)
#pragma unroll
      for (int nf = 0; nf < 4; ++nf)
        acc[mf][nf] = __builtin_amdgcn_mfma_f32_16x16x32_bf16(af[mf], bfr[nf], acc[mf][nf], 0, 0, 0);
    __syncthreads();
  }
#pragma unroll
  for (int mf = 0; mf < 4; ++mf)
#pragma unroll
    for (int nf = 0; nf < 4; ++nf) {
      int col = n0 + wn * 64 + nf * 16 + r;
      int row0 = m0 + wm * 64 + mf * 16 + g * 4;
#pragma unroll
      for (int rg = 0; rg < 4; ++rg)
        out[(size_t)(row0 + rg) * 1024 + col] = acc[mf][nf][rg];
    }
}

extern "C" void kernel_launch(void* const* d_in, const int* in_sizes, int n_in,
                              void* d_out, int out_size, void* d_ws, size_t ws_size,
                              hipStream_t stream) {
  const float* x1 = (const float*)d_in[0];
  const float* x2 = (const float*)d_in[1];
  const float* wq = (const float*)d_in[2];
  const float* bq = (const float*)d_in[3];
  const float* wk = (const float*)d_in[4];
  const float* bk = (const float*)d_in[5];
  const float* wv = (const float*)d_in[6];
  const float* bv = (const float*)d_in[7];
  const float* wp = (const float*)d_in[8];
  float* out = (float*)d_out;
  char* ws = (char*)d_ws;

  unsigned short* x1b = (unsigned short*)(ws + WS_X1B);
  unsigned short* x2b = (unsigned short*)(ws + WS_X2B);
  unsigned short* wqb = (unsigned short*)(ws + WS_W);
  unsigned short* wpb = wqb + 3 * 1048576;
  float* ctab = (float*)(ws + WS_CTAB);
  float* stab = (float*)(ws + WS_STAB);
  unsigned short* Qd = (unsigned short*)(ws + WS_Q);
  unsigned short* Kd = (unsigned short*)(ws + WS_K);
  unsigned short* VTd = (unsigned short*)(ws + WS_VT);
  unsigned short* Od = (unsigned short*)(ws + WS_O);

  cvt_kernel<<<12288, 256, 0, stream>>>(x1, x2, wq, wk, wv, wp, x1b, x2b, wqb);
  tab_kernel<<<256, 256, 0, stream>>>(ctab, stab);
  qkv_gemm<<<dim3(8, 32, 3), 256, 0, stream>>>(x1b, x2b, wqb, bq, bk, bv, ctab, stab, Qd, Kd, VTd);
  attn_kernel<<<dim3(32, 16), 256, 0, stream>>>(Qd, Kd, VTd, Od);
  proj_gemm<<<dim3(8, 32), 256, 0, stream>>>(Od, wpb, out);
}